// Round 9
// baseline (400.676 us; speedup 1.0000x reference)
//
#include <hip/hip_runtime.h>
#include <math.h>

#define HID 256
#define EMB 64
#define KTOT 320            // HID + EMB
#define MT 32               // words per block
#define NBLK 256            // 1 block per CU
#define THREADS 512         // 8 waves
#define KT 10               // k-tiles of 32
#define XSTR 328            // Xs row stride (f16): 656B, 16B-aligned, 2-way banks max

typedef _Float16 f16;
typedef _Float16 f16x4 __attribute__((ext_vector_type(4)));
typedef _Float16 f16x8 __attribute__((ext_vector_type(8)));
typedef float f32x4 __attribute__((ext_vector_type(4)));

__device__ __forceinline__ float sigm(float x) { return 1.0f / (1.0f + __expf(-x)); }
__device__ __forceinline__ float tanh_fast(float x) {
  return 1.0f - 2.0f / (__expf(2.0f * x) + 1.0f);
}

// LDS-only barrier: drain LDS ops, keep global/DMA loads in flight across it.
__device__ __forceinline__ void bar_lds() {
  asm volatile("s_waitcnt lgkmcnt(0)" ::: "memory");
  __builtin_amdgcn_sched_barrier(0);
  __builtin_amdgcn_s_barrier();
  __builtin_amdgcn_sched_barrier(0);
}

// Wfrag2 = exact LDS image, f16 index:
//   kt*32768 + wv*4096 + f*512 + lane*8 + e
// content = Wcat[g][k] with g = q*256+u; wv = u>>5, f = q*2+((u>>4)&1), r15 = u&15;
// kt = k>>5, c4 = (k>>3)&3, e = k&7, lane = c4*16 + r15.
// Wave wv's fragment f, lane L reads B[col=wv*128+f*16+(L&15)][k=kt*32+(L>>4)*8+e].
__global__ __launch_bounds__(KTOT) void prep_w(const float* __restrict__ W_ih,
                                               const float* __restrict__ W_hh,
                                               const float* __restrict__ b_ih,
                                               const float* __restrict__ b_hh,
                                               f16* __restrict__ Wfrag2,
                                               float* __restrict__ bias_p) {
  const int g = blockIdx.x;           // 0..1023
  const int k = threadIdx.x;          // 0..319
  const int q = g >> 8, u = g & 255;
  const int wv  = u >> 5;
  const int f   = q * 2 + ((u >> 4) & 1);
  const int r15 = u & 15;
  const int kt = k >> 5, c4 = (k >> 3) & 3, e = k & 7;
  const int lane = c4 * 16 + r15;
  const float w = (k < HID) ? W_hh[g * HID + k] : W_ih[g * EMB + (k - HID)];
  Wfrag2[(size_t)kt * 32768 + wv * 4096 + f * 512 + lane * 8 + e] = (f16)w;
  if (k == 0) bias_p[wv * 128 + f * 16 + r15] = b_ih[g] + b_hh[g];
}

__global__ __launch_bounds__(THREADS, 2) void lstm_mfma(
    const int* __restrict__ chars, const int* __restrict__ wordlens,
    const int* __restrict__ orig_idx, const float* __restrict__ emb_table,
    const float* __restrict__ attn_w, const float* __restrict__ h_init,
    const float* __restrict__ c_init, const f16* __restrict__ Wfrag2,
    const float* __restrict__ bias_p, float* __restrict__ out) {
  __shared__ __align__(16) f16 Bs[2][32768];     // 128 KiB: double-buffered B kt-slices (DMA dest)
  __shared__ __align__(16) f16 Xs[MT * XSTR];    // [m][k]: k<256 = h_{t-1}, k>=256 = x_t
  __shared__ __align__(16) float attP[MT * 8];   // [word][wave] attention partials
  __shared__ int chars_s[MT * 16];
  __shared__ int len_s[MT];
  __shared__ int oidx_s[MT];

  const int tid  = threadIdx.x;
  const int w0   = blockIdx.x * MT;
  const int lane = tid & 63;
  const int wv   = tid >> 6;          // 0..7, owns cols [wv*128, wv*128+128)
  const int r15  = lane & 15, c4 = lane >> 4;
  const int u0   = wv * 32 + r15;     // unit owned (s=0); s=1 -> u0+16

  chars_s[tid] = chars[w0 * 16 + tid];
  if (tid < MT) { len_s[tid] = wordlens[w0 + tid]; oidx_s[tid] = orig_idx[w0 + tid]; }

  // init Xs h-region with h_init
  {
    const int j = tid & 255, mb = tid >> 8;
    const f16 hv = (f16)h_init[j];
#pragma unroll
    for (int mm = 0; mm < 16; ++mm) Xs[(mb + mm * 2) * XSTR + j] = hv;
  }
  // stage x_0 (chars from global; chars_s not yet visible). 16 threads/word.
  {
    const int m = tid >> 4, e4 = tid & 15;
    const int ch_g = chars[(w0 + m) * 16 + 0];
    const float4 e = ((const float4*)emb_table)[ch_g * 16 + e4];
    f16x4 ev = { (f16)e.x, (f16)e.y, (f16)e.z, (f16)e.w };
    *(f16x4*)&Xs[m * XSTR + HID + e4 * 4] = ev;
  }

  const float aw0 = attn_w[u0];
  const float aw1 = attn_w[u0 + 16];
  float biasr[4][2];
#pragma unroll
  for (int q = 0; q < 4; ++q) {
    biasr[q][0] = bias_p[wv * 128 + (q * 2 + 0) * 16 + r15];
    biasr[q][1] = bias_p[wv * 128 + (q * 2 + 1) * 16 + r15];
  }

  float c_reg[2][8], res[2][8], h_new[2][8];
  {
    const float c0 = c_init[u0], c1 = c_init[u0 + 16];
#pragma unroll
    for (int i = 0; i < 8; ++i) {
      c_reg[0][i] = c0; c_reg[1][i] = c1;
      res[0][i] = 0.0f; res[1][i] = 0.0f;
      h_new[0][i] = 0.0f; h_new[1][i] = 0.0f;
    }
  }

  // ---- DMA prologue: stage kt=0 -> Bs[0], kt=1 -> Bs[1]. Each wave stages ONLY
  // the 8KB slice it reads (wv*4096 f16) -> no cross-wave hazard, no barriers.
  const f16* __restrict__ srcW = Wfrag2 + (size_t)wv * 4096 + lane * 8;
#pragma unroll
  for (int i = 0; i < 8; ++i)
    __builtin_amdgcn_global_load_lds(
        (const __attribute__((address_space(1))) unsigned int*)(srcW + 0 * 32768 + i * 512),
        (__attribute__((address_space(3))) unsigned int*)(&Bs[0][wv * 4096 + i * 512]),
        16, 0, 0);
#pragma unroll
  for (int i = 0; i < 8; ++i)
    __builtin_amdgcn_global_load_lds(
        (const __attribute__((address_space(1))) unsigned int*)(srcW + 1 * 32768 + i * 512),
        (__attribute__((address_space(3))) unsigned int*)(&Bs[1][wv * 4096 + i * 512]),
        16, 0, 0);

  __syncthreads();   // init barrier (full drain once is fine)

  int steps = 1;
#pragma unroll
  for (int m = 0; m < MT; ++m) steps = max(steps, len_s[m]);
  int lenr[8];
#pragma unroll
  for (int mt = 0; mt < 2; ++mt)
#pragma unroll
    for (int r = 0; r < 4; ++r) lenr[mt * 4 + r] = len_s[mt * 16 + c4 * 4 + r];

  for (int t = 0; t < steps; ++t) {
    // prefetch x_{t+1} embedding rows early (use deferred to post-loop)
    float4 embnx;
    const bool have_nx = (t + 1 < steps);
    if (have_nx) {
      const int m = tid >> 4, e4 = tid & 15;
      const int ch = chars_s[m * 16 + (t + 1)];
      embnx = ((const float4*)emb_table)[ch * 16 + e4];
    }

    f32x4 acc[4][2];   // [gate q][unit-half s] x (words via 16x16 rows)
    f32x4 acc2[4][2];  // second m-tile
#pragma unroll
    for (int q = 0; q < 4; ++q)
#pragma unroll
      for (int s = 0; s < 2; ++s) {
        const float b = biasr[q][s];
        const f32x4 b4 = { b, b, b, b };
        acc[q][s] = b4; acc2[q][s] = b4;
      }

#pragma unroll
    for (int kt = 0; kt < KT; ++kt) {
      // wait for MY stage(kt) to land (8 newer stage loads may float)
      asm volatile("s_waitcnt vmcnt(8)" ::: "memory");
      __builtin_amdgcn_sched_barrier(0);

      const f16* __restrict__ bsl = &Bs[kt & 1][wv * 4096 + lane * 8];
      f16x8 bb[8];
#pragma unroll
      for (int f = 0; f < 8; ++f) bb[f] = *(const f16x8*)(bsl + f * 512);
      const f16x8 a0 = *(const f16x8*)&Xs[r15 * XSTR + kt * 32 + c4 * 8];
      const f16x8 a1 = *(const f16x8*)&Xs[(16 + r15) * XSTR + kt * 32 + c4 * 8];

      // my reads must COMPLETE before re-staging this buffer region
      asm volatile("s_waitcnt lgkmcnt(0)" ::: "memory");
      __builtin_amdgcn_sched_barrier(0);

      // stage kt+2 (or next step's kt+2-KT) into the just-freed buffer region
      {
        const int ktn = (kt + 2 < KT) ? (kt + 2) : (kt + 2 - KT);
        const f16* __restrict__ s2 = srcW + (size_t)ktn * 32768;
#pragma unroll
        for (int i = 0; i < 8; ++i)
          __builtin_amdgcn_global_load_lds(
              (const __attribute__((address_space(1))) unsigned int*)(s2 + i * 512),
              (__attribute__((address_space(3))) unsigned int*)(&Bs[kt & 1][wv * 4096 + i * 512]),
              16, 0, 0);
      }

#pragma unroll
      for (int q = 0; q < 4; ++q)
#pragma unroll
        for (int s = 0; s < 2; ++s) {
          acc[q][s]  = __builtin_amdgcn_mfma_f32_16x16x32_f16(a0, bb[q * 2 + s], acc[q][s],  0, 0, 0);
          acc2[q][s] = __builtin_amdgcn_mfma_f32_16x16x32_f16(a1, bb[q * 2 + s], acc2[q][s], 0, 0, 0);
        }
    }

    // ---- LSTM cell in registers: lane owns units u0,u0+16, words mt*16+c4*4+r
#pragma unroll
    for (int s = 0; s < 2; ++s)
#pragma unroll
      for (int r = 0; r < 4; ++r) {
        {
          const float cc = sigm(acc[1][s][r]) * c_reg[s][r] + sigm(acc[0][s][r]) * tanh_fast(acc[2][s][r]);
          c_reg[s][r] = cc;
          h_new[s][r] = sigm(acc[3][s][r]) * tanh_fast(cc);
        }
        {
          const int i = 4 + r;
          const float cc = sigm(acc2[1][s][r]) * c_reg[s][i] + sigm(acc2[0][s][r]) * tanh_fast(acc2[2][s][r]);
          c_reg[s][i] = cc;
          h_new[s][i] = sigm(acc2[3][s][r]) * tanh_fast(cc);
        }
      }

    bar_lds();   // all A-reads of this step done (lgkm 0 at each kt); Xs/attP writable

    // write h_t -> Xs; stage x_{t+1} (from prefetched embnx)
    if (have_nx) {
#pragma unroll
      for (int s = 0; s < 2; ++s)
#pragma unroll
        for (int mt = 0; mt < 2; ++mt)
#pragma unroll
          for (int r = 0; r < 4; ++r)
            Xs[(mt * 16 + c4 * 4 + r) * XSTR + u0 + s * 16] = (f16)h_new[s][mt * 4 + r];
      {
        const int m = tid >> 4, e4 = tid & 15;
        f16x4 ev = { (f16)embnx.x, (f16)embnx.y, (f16)embnx.z, (f16)embnx.w };
        *(f16x4*)&Xs[m * XSTR + HID + e4 * 4] = ev;
      }
    }

    // attention partials: this wave's 32 units, butterfly over r15 group
#pragma unroll
    for (int mt = 0; mt < 2; ++mt)
#pragma unroll
      for (int r = 0; r < 4; ++r) {
        const int i = mt * 4 + r;
        float p = h_new[0][i] * aw0 + h_new[1][i] * aw1;
        p += __shfl_xor(p, 1); p += __shfl_xor(p, 2);
        p += __shfl_xor(p, 4); p += __shfl_xor(p, 8);
        if (r15 == 0) attP[(mt * 16 + c4 * 4 + r) * 8 + wv] = p;
      }

    bar_lds();

    // redundant per-lane weight: read 8 wave-partials (broadcast), sigm, mask, accumulate
#pragma unroll
    for (int mt = 0; mt < 2; ++mt)
#pragma unroll
      for (int r = 0; r < 4; ++r) {
        const int i = mt * 4 + r;
        const int w = mt * 16 + c4 * 4 + r;
        const f32x4 p0 = *(const f32x4*)&attP[w * 8];
        const f32x4 p1 = *(const f32x4*)&attP[w * 8 + 4];
        const float sum = (p0[0] + p0[1]) + (p0[2] + p0[3]) + (p1[0] + p1[1]) + (p1[2] + p1[3]);
        const float wgt = (t < lenr[i]) ? sigm(sum) : 0.0f;
        res[0][i] = fmaf(wgt, h_new[0][i], res[0][i]);
        res[1][i] = fmaf(wgt, h_new[1][i], res[1][i]);
      }
  }

  // ---- tensor_unsort + write
#pragma unroll
  for (int s = 0; s < 2; ++s)
#pragma unroll
    for (int mt = 0; mt < 2; ++mt)
#pragma unroll
      for (int r = 0; r < 4; ++r) {
        const int w = mt * 16 + c4 * 4 + r;
        out[(size_t)oidx_s[w] * HID + u0 + s * 16] = res[s][mt * 4 + r];
      }
}

extern "C" void kernel_launch(void* const* d_in, const int* in_sizes, int n_in,
                              void* d_out, int out_size, void* d_ws, size_t ws_size,
                              hipStream_t stream) {
  const int*   chars    = (const int*)d_in[0];
  const int*   wordlens = (const int*)d_in[1];
  const int*   orig_idx = (const int*)d_in[2];
  const float* emb      = (const float*)d_in[3];
  const float* W_ih     = (const float*)d_in[4];
  const float* W_hh     = (const float*)d_in[5];
  const float* b_ih     = (const float*)d_in[6];
  const float* b_hh     = (const float*)d_in[7];
  const float* attn_w   = (const float*)d_in[8];
  const float* h_init   = (const float*)d_in[9];
  const float* c_init   = (const float*)d_in[10];
  float* out = (float*)d_out;

  f16*   Wfrag2 = (f16*)d_ws;                      // 10*32768 f16 = 640 KiB (LDS image)
  float* bias_p = (float*)((char*)d_ws + (size_t)KT * 32768 * sizeof(f16));
  if (ws_size < (size_t)KT * 32768 * sizeof(f16) + 1024 * sizeof(float)) return;

  hipLaunchKernelGGL(prep_w, dim3(1024), dim3(KTOT), 0, stream,
                     W_ih, W_hh, b_ih, b_hh, Wfrag2, bias_p);
  hipLaunchKernelGGL(lstm_mfma, dim3(NBLK), dim3(THREADS), 0, stream,
                     chars, wordlens, orig_idx, emb, attn_w, h_init, c_init,
                     Wfrag2, bias_p, out);
}

// Round 10
// 378.728 us; speedup vs baseline: 1.0580x; 1.0580x over previous
//
#include <hip/hip_runtime.h>
#include <math.h>

#define HID 256
#define EMB 64
#define KTOT 320            // HID + EMB
#define MT 32               // words per block
#define NBLK 256            // 1 block per CU (also forced by ~90KB LDS)
#define THREADS 512         // 8 waves = 2 waves/SIMD
#define KT 10               // k-tiles of 32
#define KT_STREAM 5         // kt 0..4 streamed from L2 each step (320KB/CU/step)
#define KT_REG 4            // kt 5..8 resident in registers (128 VGPR/AGPR)
                            // kt 9 resident in LDS (64KB)
#define XSTR 328            // Xs row stride (f16): 656B, 16B-aligned

typedef _Float16 f16;
typedef _Float16 f16x4 __attribute__((ext_vector_type(4)));
typedef _Float16 f16x8 __attribute__((ext_vector_type(8)));
typedef float f32x4 __attribute__((ext_vector_type(4)));

__device__ __forceinline__ float sigm(float x) { return 1.0f / (1.0f + __expf(-x)); }
__device__ __forceinline__ float tanh_fast(float x) {
  return 1.0f - 2.0f / (__expf(2.0f * x) + 1.0f);
}

// Wfrag: R5 layout. col = wv*128 + q*32 + s*16 + r15 (wv=u>>5, s=(u>>4)&1, r15=u&15)
//   Wfrag[(kt*1024 + col)*32 + (k&31)] = f16(Wcat[g][k]), Wcat = [W_hh | W_ih]
// Wlds (kt 9 only), lane-linear for conflict-free ds_read_b128:
//   f16x8 idx = wv*512 + (q*2+s)*64 + c4*16 + r15,  elem e = k&7, c4 = (k>>3)&3
__global__ __launch_bounds__(KTOT) void prep_w(const float* __restrict__ W_ih,
                                               const float* __restrict__ W_hh,
                                               const float* __restrict__ b_ih,
                                               const float* __restrict__ b_hh,
                                               f16* __restrict__ Wfrag,
                                               f16* __restrict__ Wlds,
                                               float* __restrict__ bias_p) {
  const int g = blockIdx.x;           // 0..1023
  const int k = threadIdx.x;          // 0..319
  const int q = g >> 8, u = g & 255;
  const int wv  = u >> 5;
  const int s   = (u >> 4) & 1;
  const int r15 = u & 15;
  const int col = wv * 128 + q * 32 + s * 16 + r15;
  const float w = (k < HID) ? W_hh[g * HID + k] : W_ih[g * EMB + (k - HID)];
  const int kt = k >> 5;
  Wfrag[((size_t)(kt * 1024 + col)) * 32 + (k & 31)] = (f16)w;
  if (kt == 9) {
    const int c4 = (k >> 3) & 3, e = k & 7;
    const int fidx = q * 2 + s;
    Wlds[((size_t)(wv * 512 + fidx * 64 + c4 * 16 + r15) << 3) + e] = (f16)w;
  }
  if (k == 0) bias_p[col] = b_ih[g] + b_hh[g];
}

__global__ __launch_bounds__(THREADS)
__attribute__((amdgpu_waves_per_eu(2, 2)))   // pin 2 waves/SIMD -> up to 256 VGPR+AGPR
void lstm_mfma(
    const int* __restrict__ chars, const int* __restrict__ wordlens,
    const int* __restrict__ orig_idx, const float* __restrict__ emb_table,
    const float* __restrict__ attn_w, const float* __restrict__ h_init,
    const float* __restrict__ c_init, const f16* __restrict__ Wfrag,
    const f16* __restrict__ Wlds, const float* __restrict__ bias_p,
    float* __restrict__ out) {
  __shared__ __align__(16) f16 LBs[32768];      // 64KB: kt=9 weights, LDS-resident
  __shared__ __align__(16) f16 Xs[MT * XSTR];   // [m][k]: k<256 = h_{t-1}, k>=256 = x_t
  __shared__ __align__(16) float attP[MT * 8];  // [word][wave] attention partials
  __shared__ int chars_s[MT * 16];
  __shared__ int len_s[MT];
  __shared__ int oidx_s[MT];

  const int tid  = threadIdx.x;
  const int w0   = blockIdx.x * MT;
  const int lane = tid & 63;
  const int wv   = tid >> 6;          // 0..7, owns cols [wv*128, wv*128+128)
  const int r15  = lane & 15, c4 = lane >> 4;
  const int u0   = wv * 32 + r15;     // unit owned (s=0); s=1 -> u0+16

  chars_s[tid] = chars[w0 * 16 + tid];
  if (tid < MT) { len_s[tid] = wordlens[w0 + tid]; oidx_s[tid] = orig_idx[w0 + tid]; }

  // copy kt=9 weight slice into LDS (one time, coalesced both sides)
  {
    const f16x8* __restrict__ src = (const f16x8*)Wlds;
    f16x8* __restrict__ dst = (f16x8*)LBs;
#pragma unroll
    for (int i = 0; i < 8; ++i) dst[tid * 8 + i] = src[tid * 8 + i];
  }

  // init Xs h-region with h_init
  {
    const int j = tid & 255, mb = tid >> 8;
    const f16 hv = (f16)h_init[j];
#pragma unroll
    for (int mm = 0; mm < 16; ++mm) Xs[(mb + mm * 2) * XSTR + j] = hv;
  }
  // stage x_0 (chars from global; chars_s not yet visible). 16 threads/word.
  {
    const int m = tid >> 4, e4 = tid & 15;
    const int ch_g = chars[(w0 + m) * 16 + 0];
    const float4 e = ((const float4*)emb_table)[ch_g * 16 + e4];
    f16x4 ev = { (f16)e.x, (f16)e.y, (f16)e.z, (f16)e.w };
    *(f16x4*)&Xs[m * XSTR + HID + e4 * 4] = ev;
  }

  const float aw0 = attn_w[u0];
  const float aw1 = attn_w[u0 + 16];
  float biasr[4][2];
#pragma unroll
  for (int q = 0; q < 4; ++q) {
    biasr[q][0] = bias_p[wv * 128 + q * 32 + r15];
    biasr[q][1] = bias_p[wv * 128 + q * 32 + 16 + r15];
  }

  float c_reg[2][8], res[2][8], h_new[2][8];
  {
    const float c0 = c_init[u0], c1 = c_init[u0 + 16];
#pragma unroll
    for (int i = 0; i < 8; ++i) {
      c_reg[0][i] = c0; c_reg[1][i] = c1;
      res[0][i] = 0.0f; res[1][i] = 0.0f;
      h_new[0][i] = 0.0f; h_new[1][i] = 0.0f;
    }
  }

  // B index (f16x8 units): bofs + (q*32 + s*16)*4 within a kt
  const size_t bofs = (size_t)(wv * 128 + r15) * 4 + c4;

  // ---- register-resident tier: kt = 5..8 loaded ONCE (128 regs, MFMA operands)
  f16x8 Wr[KT_REG][8];
#pragma unroll
  for (int kt = 0; kt < KT_REG; ++kt) {
    const f16x8* __restrict__ Wp = ((const f16x8*)Wfrag) + (size_t)(KT_STREAM + kt) * 4096;
#pragma unroll
    for (int f = 0; f < 8; ++f) Wr[kt][f] = Wp[bofs + (size_t)f * 64];
  }

  __syncthreads();

  int steps = 1;
#pragma unroll
  for (int m = 0; m < MT; ++m) steps = max(steps, len_s[m]);
  int lenr[8];
#pragma unroll
  for (int mt = 0; mt < 2; ++mt)
#pragma unroll
    for (int r = 0; r < 4; ++r) lenr[mt * 4 + r] = len_s[mt * 16 + c4 * 4 + r];

  for (int t = 0; t < steps; ++t) {
    f32x4 acc[4][2][2];   // [gate q][unit-half s][m-tile mt]
#pragma unroll
    for (int q = 0; q < 4; ++q)
#pragma unroll
      for (int s = 0; s < 2; ++s) {
        const float b = biasr[q][s];
        const f32x4 b4 = { b, b, b, b };
        acc[q][s][0] = b4; acc[q][s][1] = b4;
      }

    // ---- streamed tier: kt = 0..4 from L2 (320KB/CU/step)
#pragma unroll 2
    for (int kt = 0; kt < KT_STREAM; ++kt) {
      const f16x8* __restrict__ Wp = ((const f16x8*)Wfrag) + (size_t)kt * 4096;
      f16x8 bb[8];
#pragma unroll
      for (int f = 0; f < 8; ++f) bb[f] = Wp[bofs + (size_t)f * 64];
      const f16x8 a0 = *(const f16x8*)&Xs[r15 * XSTR + kt * 32 + c4 * 8];
      const f16x8 a1 = *(const f16x8*)&Xs[(16 + r15) * XSTR + kt * 32 + c4 * 8];
#pragma unroll
      for (int q = 0; q < 4; ++q)
#pragma unroll
        for (int s = 0; s < 2; ++s) {
          acc[q][s][0] = __builtin_amdgcn_mfma_f32_16x16x32_f16(a0, bb[q * 2 + s], acc[q][s][0], 0, 0, 0);
          acc[q][s][1] = __builtin_amdgcn_mfma_f32_16x16x32_f16(a1, bb[q * 2 + s], acc[q][s][1], 0, 0, 0);
        }
    }

    // ---- register tier: kt = 5..8 (no memory traffic)
#pragma unroll
    for (int kt = 0; kt < KT_REG; ++kt) {
      const int kk = KT_STREAM + kt;
      const f16x8 a0 = *(const f16x8*)&Xs[r15 * XSTR + kk * 32 + c4 * 8];
      const f16x8 a1 = *(const f16x8*)&Xs[(16 + r15) * XSTR + kk * 32 + c4 * 8];
#pragma unroll
      for (int q = 0; q < 4; ++q)
#pragma unroll
        for (int s = 0; s < 2; ++s) {
          acc[q][s][0] = __builtin_amdgcn_mfma_f32_16x16x32_f16(a0, Wr[kt][q * 2 + s], acc[q][s][0], 0, 0, 0);
          acc[q][s][1] = __builtin_amdgcn_mfma_f32_16x16x32_f16(a1, Wr[kt][q * 2 + s], acc[q][s][1], 0, 0, 0);
        }
    }

    // ---- LDS tier: kt = 9 (conflict-free lane-linear ds_read_b128)
    {
      const f16x8* __restrict__ bsl = ((const f16x8*)LBs) + wv * 512 + c4 * 16 + r15;
      const f16x8 a0 = *(const f16x8*)&Xs[r15 * XSTR + 9 * 32 + c4 * 8];
      const f16x8 a1 = *(const f16x8*)&Xs[(16 + r15) * XSTR + 9 * 32 + c4 * 8];
#pragma unroll
      for (int q = 0; q < 4; ++q)
#pragma unroll
        for (int s = 0; s < 2; ++s) {
          const f16x8 b = bsl[(q * 2 + s) * 64];
          acc[q][s][0] = __builtin_amdgcn_mfma_f32_16x16x32_f16(a0, b, acc[q][s][0], 0, 0, 0);
          acc[q][s][1] = __builtin_amdgcn_mfma_f32_16x16x32_f16(a1, b, acc[q][s][1], 0, 0, 0);
        }
    }

    // ---- LSTM cell in registers: lane owns units u0,u0+16, words mt*16+c4*4+r
#pragma unroll
    for (int s = 0; s < 2; ++s)
#pragma unroll
      for (int mt = 0; mt < 2; ++mt)
#pragma unroll
        for (int r = 0; r < 4; ++r) {
          const int i = mt * 4 + r;
          const float gi = acc[0][s][mt][r];
          const float gf = acc[1][s][mt][r];
          const float gg = acc[2][s][mt][r];
          const float go = acc[3][s][mt][r];
          const float cc = sigm(gf) * c_reg[s][i] + sigm(gi) * tanh_fast(gg);
          c_reg[s][i] = cc;
          h_new[s][i] = sigm(go) * tanh_fast(cc);
        }

    __syncthreads();   // A-reads of this step done; Xs/attP writable

    // write h_t -> Xs; stage x_{t+1}
    if (t + 1 < steps) {
#pragma unroll
      for (int s = 0; s < 2; ++s)
#pragma unroll
        for (int mt = 0; mt < 2; ++mt)
#pragma unroll
          for (int r = 0; r < 4; ++r)
            Xs[(mt * 16 + c4 * 4 + r) * XSTR + u0 + s * 16] = (f16)h_new[s][mt * 4 + r];
      {
        const int m = tid >> 4, e4 = tid & 15;
        const int ch = chars_s[m * 16 + (t + 1)];
        const float4 e = ((const float4*)emb_table)[ch * 16 + e4];
        f16x4 ev = { (f16)e.x, (f16)e.y, (f16)e.z, (f16)e.w };
        *(f16x4*)&Xs[m * XSTR + HID + e4 * 4] = ev;
      }
    }

    // attention partials: this wave's 32 units, butterfly over r15 group
#pragma unroll
    for (int mt = 0; mt < 2; ++mt)
#pragma unroll
      for (int r = 0; r < 4; ++r) {
        const int i = mt * 4 + r;
        float p = h_new[0][i] * aw0 + h_new[1][i] * aw1;
        p += __shfl_xor(p, 1); p += __shfl_xor(p, 2);
        p += __shfl_xor(p, 4); p += __shfl_xor(p, 8);
        if (r15 == 0) attP[(mt * 16 + c4 * 4 + r) * 8 + wv] = p;
      }

    __syncthreads();

    // redundant per-lane weight: read 8 wave-partials (broadcast), sigm, mask, accumulate
#pragma unroll
    for (int mt = 0; mt < 2; ++mt)
#pragma unroll
      for (int r = 0; r < 4; ++r) {
        const int i = mt * 4 + r;
        const int w = mt * 16 + c4 * 4 + r;
        const f32x4 p0 = *(const f32x4*)&attP[w * 8];
        const f32x4 p1 = *(const f32x4*)&attP[w * 8 + 4];
        const float sum = (p0[0] + p0[1]) + (p0[2] + p0[3]) + (p1[0] + p1[1]) + (p1[2] + p1[3]);
        const float wgt = (t < lenr[i]) ? sigm(sum) : 0.0f;
        res[0][i] = fmaf(wgt, h_new[0][i], res[0][i]);
        res[1][i] = fmaf(wgt, h_new[1][i], res[1][i]);
      }
  }

  // ---- tensor_unsort + write
#pragma unroll
  for (int s = 0; s < 2; ++s)
#pragma unroll
    for (int mt = 0; mt < 2; ++mt)
#pragma unroll
      for (int r = 0; r < 4; ++r) {
        const int w = mt * 16 + c4 * 4 + r;
        out[(size_t)oidx_s[w] * HID + u0 + s * 16] = res[s][mt * 4 + r];
      }
}

extern "C" void kernel_launch(void* const* d_in, const int* in_sizes, int n_in,
                              void* d_out, int out_size, void* d_ws, size_t ws_size,
                              hipStream_t stream) {
  const int*   chars    = (const int*)d_in[0];
  const int*   wordlens = (const int*)d_in[1];
  const int*   orig_idx = (const int*)d_in[2];
  const float* emb      = (const float*)d_in[3];
  const float* W_ih     = (const float*)d_in[4];
  const float* W_hh     = (const float*)d_in[5];
  const float* b_ih     = (const float*)d_in[6];
  const float* b_hh     = (const float*)d_in[7];
  const float* attn_w   = (const float*)d_in[8];
  const float* h_init   = (const float*)d_in[9];
  const float* c_init   = (const float*)d_in[10];
  float* out = (float*)d_out;

  const size_t wfrag_elems = (size_t)KT * 1024 * 32;     // 327680 f16
  const size_t wlds_elems  = 32768;                      // 64KB f16
  f16*   Wfrag  = (f16*)d_ws;
  f16*   Wlds   = Wfrag + wfrag_elems;
  float* bias_p = (float*)(Wlds + wlds_elems);
  if (ws_size < (wfrag_elems + wlds_elems) * sizeof(f16) + 1024 * sizeof(float)) return;

  hipLaunchKernelGGL(prep_w, dim3(1024), dim3(KTOT), 0, stream,
                     W_ih, W_hh, b_ih, b_hh, Wfrag, Wlds, bias_p);
  hipLaunchKernelGGL(lstm_mfma, dim3(NBLK), dim3(THREADS), 0, stream,
                     chars, wordlens, orig_idx, emb, attn_w, h_init, c_init,
                     Wfrag, Wlds, bias_p, out);
}

// Round 11
// 353.515 us; speedup vs baseline: 1.1334x; 1.0713x over previous
//
#include <hip/hip_runtime.h>
#include <math.h>

#define HID 256
#define EMB 64
#define KTOT 320            // HID + EMB
#define MT 32               // words per block
#define NBLK 256            // 1 block per CU (forced by 152KB LDS)
#define THREADS 512         // 8 waves = 2 waves/SIMD
#define KT 10               // k-tiles of 32

#define XSTR 328            // Xs row stride (f16): 656B, 16B-aligned

typedef _Float16 f16;
typedef _Float16 f16x4 __attribute__((ext_vector_type(4)));
typedef _Float16 f16x8 __attribute__((ext_vector_type(8)));
typedef float f32x4 __attribute__((ext_vector_type(4)));

__device__ __forceinline__ float sigm(float x) { return 1.0f / (1.0f + __expf(-x)); }
__device__ __forceinline__ float tanh_fast(float x) {
  return 1.0f - 2.0f / (__expf(2.0f * x) + 1.0f);
}

// Wfrag2 = exact LDS image (R9 layout, HW-verified correct), f16 index:
//   kt*32768 + wv*4096 + f*512 + lane*8 + e
// g = q*256+u; wv = u>>5, f = q*2+((u>>4)&1), r15 = u&15;
// kt = k>>5, c4 = (k>>3)&3, e = k&7, lane = c4*16 + r15.
__global__ __launch_bounds__(KTOT) void prep_w(const float* __restrict__ W_ih,
                                               const float* __restrict__ W_hh,
                                               const float* __restrict__ b_ih,
                                               const float* __restrict__ b_hh,
                                               f16* __restrict__ Wfrag2,
                                               float* __restrict__ bias_p) {
  const int g = blockIdx.x;           // 0..1023
  const int k = threadIdx.x;          // 0..319
  const int q = g >> 8, u = g & 255;
  const int wv  = u >> 5;
  const int f   = q * 2 + ((u >> 4) & 1);
  const int r15 = u & 15;
  const int kt = k >> 5, c4 = (k >> 3) & 3, e = k & 7;
  const int lane = c4 * 16 + r15;
  const float w = (k < HID) ? W_hh[g * HID + k] : W_ih[g * EMB + (k - HID)];
  Wfrag2[(size_t)kt * 32768 + wv * 4096 + f * 512 + lane * 8 + e] = (f16)w;
  if (k == 0) bias_p[wv * 128 + f * 16 + r15] = b_ih[g] + b_hh[g];
}

__global__ __launch_bounds__(THREADS, 2) void lstm_mfma(
    const int* __restrict__ chars, const int* __restrict__ wordlens,
    const int* __restrict__ orig_idx, const float* __restrict__ emb_table,
    const float* __restrict__ attn_w, const float* __restrict__ h_init,
    const float* __restrict__ c_init, const f16* __restrict__ Wfrag2,
    const float* __restrict__ bias_p, float* __restrict__ out) {
  __shared__ __align__(16) f16 Bs[2][32768];     // 128KB: double-buffered B kt-slices (DMA dest)
  __shared__ __align__(16) f16 Xs[MT * XSTR];    // [m][k]: k<256 = h_{t-1}, k>=256 = x_t
  __shared__ __align__(16) float attP[MT * 8];   // [word][wave] attention partials
  __shared__ int chars_s[MT * 16];
  __shared__ int len_s[MT];
  __shared__ int oidx_s[MT];

  const int tid  = threadIdx.x;
  const int w0   = blockIdx.x * MT;
  const int lane = tid & 63;
  const int wv   = tid >> 6;          // 0..7, owns cols [wv*128, wv*128+128)
  const int r15  = lane & 15, c4 = lane >> 4;
  const int u0   = wv * 32 + r15;     // unit owned (s=0); s=1 -> u0+16

  chars_s[tid] = chars[w0 * 16 + tid];
  if (tid < MT) { len_s[tid] = wordlens[w0 + tid]; oidx_s[tid] = orig_idx[w0 + tid]; }

  // init Xs h-region with h_init
  {
    const int j = tid & 255, mb = tid >> 8;
    const f16 hv = (f16)h_init[j];
#pragma unroll
    for (int mm = 0; mm < 16; ++mm) Xs[(mb + mm * 2) * XSTR + j] = hv;
  }
  // stage x_0 (chars from global; chars_s not yet visible). 16 threads/word.
  {
    const int m = tid >> 4, e4 = tid & 15;
    const int ch_g = chars[(w0 + m) * 16 + 0];
    const float4 e = ((const float4*)emb_table)[ch_g * 16 + e4];
    f16x4 ev = { (f16)e.x, (f16)e.y, (f16)e.z, (f16)e.w };
    *(f16x4*)&Xs[m * XSTR + HID + e4 * 4] = ev;
  }

  const float aw0 = attn_w[u0];
  const float aw1 = attn_w[u0 + 16];
  float biasr[4][2];
#pragma unroll
  for (int q = 0; q < 4; ++q) {
    biasr[q][0] = bias_p[wv * 128 + (q * 2 + 0) * 16 + r15];
    biasr[q][1] = bias_p[wv * 128 + (q * 2 + 1) * 16 + r15];
  }

  float c_reg[2][8], res[2][8], h_new[2][8];
  {
    const float c0 = c_init[u0], c1 = c_init[u0 + 16];
#pragma unroll
    for (int i = 0; i < 8; ++i) {
      c_reg[0][i] = c0; c_reg[1][i] = c1;
      res[0][i] = 0.0f; res[1][i] = 0.0f;
      h_new[0][i] = 0.0f; h_new[1][i] = 0.0f;
    }
  }

  // ---- DMA prologue: stage kt=0 -> Bs[0], kt=1 -> Bs[1]. Each wave stages ONLY
  // the 8KB slice it reads -> no cross-wave hazard.
  const f16* __restrict__ srcW = Wfrag2 + (size_t)wv * 4096 + lane * 8;
#pragma unroll
  for (int i = 0; i < 8; ++i)
    __builtin_amdgcn_global_load_lds(
        (const __attribute__((address_space(1))) unsigned int*)(srcW + 0 * 32768 + i * 512),
        (__attribute__((address_space(3))) unsigned int*)(&Bs[0][wv * 4096 + i * 512]),
        16, 0, 0);
#pragma unroll
  for (int i = 0; i < 8; ++i)
    __builtin_amdgcn_global_load_lds(
        (const __attribute__((address_space(1))) unsigned int*)(srcW + 1 * 32768 + i * 512),
        (__attribute__((address_space(3))) unsigned int*)(&Bs[1][wv * 4096 + i * 512]),
        16, 0, 0);

  __syncthreads();   // init barrier (drains prologue stages too)

  int steps = 1;
#pragma unroll
  for (int m = 0; m < MT; ++m) steps = max(steps, len_s[m]);
  int lenr[8];
#pragma unroll
  for (int mt = 0; mt < 2; ++mt)
#pragma unroll
    for (int r = 0; r < 4; ++r) lenr[mt * 4 + r] = len_s[mt * 16 + c4 * 4 + r];

  for (int t = 0; t < steps; ++t) {
    f32x4 acc[4][2][2];   // [gate q][unit-half s][m-tile mt]
#pragma unroll
    for (int q = 0; q < 4; ++q)
#pragma unroll
      for (int s = 0; s < 2; ++s) {
        const float b = biasr[q][s];
        const f32x4 b4 = { b, b, b, b };
        acc[q][s][0] = b4; acc[q][s][1] = b4;
      }

#pragma unroll
    for (int kt = 0; kt < KT; ++kt) {
      // my stage(kt) must have landed; stage(kt+1) (8 loads) may float
      asm volatile("s_waitcnt vmcnt(8)" ::: "memory");

      const f16* __restrict__ bsl = &Bs[kt & 1][wv * 4096 + lane * 8];
      const f16x8 a0 = *(const f16x8*)&Xs[r15 * XSTR + kt * 32 + c4 * 8];
      const f16x8 a1 = *(const f16x8*)&Xs[(16 + r15) * XSTR + kt * 32 + c4 * 8];

      // first half: fragments f=0..3 (gates q=0,1)
      f16x8 b0 = *(const f16x8*)(bsl + 0 * 512);
      f16x8 b1 = *(const f16x8*)(bsl + 1 * 512);
      f16x8 b2 = *(const f16x8*)(bsl + 2 * 512);
      f16x8 b3 = *(const f16x8*)(bsl + 3 * 512);
      acc[0][0][0] = __builtin_amdgcn_mfma_f32_16x16x32_f16(a0, b0, acc[0][0][0], 0, 0, 0);
      acc[0][0][1] = __builtin_amdgcn_mfma_f32_16x16x32_f16(a1, b0, acc[0][0][1], 0, 0, 0);
      acc[0][1][0] = __builtin_amdgcn_mfma_f32_16x16x32_f16(a0, b1, acc[0][1][0], 0, 0, 0);
      acc[0][1][1] = __builtin_amdgcn_mfma_f32_16x16x32_f16(a1, b1, acc[0][1][1], 0, 0, 0);
      acc[1][0][0] = __builtin_amdgcn_mfma_f32_16x16x32_f16(a0, b2, acc[1][0][0], 0, 0, 0);
      acc[1][0][1] = __builtin_amdgcn_mfma_f32_16x16x32_f16(a1, b2, acc[1][0][1], 0, 0, 0);
      acc[1][1][0] = __builtin_amdgcn_mfma_f32_16x16x32_f16(a0, b3, acc[1][1][0], 0, 0, 0);
      acc[1][1][1] = __builtin_amdgcn_mfma_f32_16x16x32_f16(a1, b3, acc[1][1][1], 0, 0, 0);

      // second half: fragments f=4..7 (gates q=2,3)
      f16x8 b4 = *(const f16x8*)(bsl + 4 * 512);
      f16x8 b5 = *(const f16x8*)(bsl + 5 * 512);
      f16x8 b6 = *(const f16x8*)(bsl + 6 * 512);
      f16x8 b7 = *(const f16x8*)(bsl + 7 * 512);

      // ALL my LDS reads of this region done -> safe to restage it
      asm volatile("s_waitcnt lgkmcnt(0)" ::: "memory");
      {
        const int ktn = (kt + 2 < KT) ? (kt + 2) : (kt + 2 - KT);
        const f16* __restrict__ s2 = srcW + (size_t)ktn * 32768;
#pragma unroll
        for (int i = 0; i < 8; ++i)
          __builtin_amdgcn_global_load_lds(
              (const __attribute__((address_space(1))) unsigned int*)(s2 + i * 512),
              (__attribute__((address_space(3))) unsigned int*)(&Bs[kt & 1][wv * 4096 + i * 512]),
              16, 0, 0);
      }

      acc[2][0][0] = __builtin_amdgcn_mfma_f32_16x16x32_f16(a0, b4, acc[2][0][0], 0, 0, 0);
      acc[2][0][1] = __builtin_amdgcn_mfma_f32_16x16x32_f16(a1, b4, acc[2][0][1], 0, 0, 0);
      acc[2][1][0] = __builtin_amdgcn_mfma_f32_16x16x32_f16(a0, b5, acc[2][1][0], 0, 0, 0);
      acc[2][1][1] = __builtin_amdgcn_mfma_f32_16x16x32_f16(a1, b5, acc[2][1][1], 0, 0, 0);
      acc[3][0][0] = __builtin_amdgcn_mfma_f32_16x16x32_f16(a0, b6, acc[3][0][0], 0, 0, 0);
      acc[3][0][1] = __builtin_amdgcn_mfma_f32_16x16x32_f16(a1, b6, acc[3][0][1], 0, 0, 0);
      acc[3][1][0] = __builtin_amdgcn_mfma_f32_16x16x32_f16(a0, b7, acc[3][1][0], 0, 0, 0);
      acc[3][1][1] = __builtin_amdgcn_mfma_f32_16x16x32_f16(a1, b7, acc[3][1][1], 0, 0, 0);
    }

    // ---- LSTM cell in registers: lane owns units u0,u0+16, words mt*16+c4*4+r
#pragma unroll
    for (int s = 0; s < 2; ++s)
#pragma unroll
      for (int mt = 0; mt < 2; ++mt)
#pragma unroll
        for (int r = 0; r < 4; ++r) {
          const int i = mt * 4 + r;
          const float gi = acc[0][s][mt][r];
          const float gf = acc[1][s][mt][r];
          const float gg = acc[2][s][mt][r];
          const float go = acc[3][s][mt][r];
          const float cc = sigm(gf) * c_reg[s][i] + sigm(gi) * tanh_fast(gg);
          c_reg[s][i] = cc;
          h_new[s][i] = sigm(go) * tanh_fast(cc);
        }

    __syncthreads();   // A-reads of this step done; Xs/attP writable

    // write h_t -> Xs; stage x_{t+1}
    if (t + 1 < steps) {
#pragma unroll
      for (int s = 0; s < 2; ++s)
#pragma unroll
        for (int mt = 0; mt < 2; ++mt)
#pragma unroll
          for (int r = 0; r < 4; ++r)
            Xs[(mt * 16 + c4 * 4 + r) * XSTR + u0 + s * 16] = (f16)h_new[s][mt * 4 + r];
      {
        const int m = tid >> 4, e4 = tid & 15;
        const int ch = chars_s[m * 16 + (t + 1)];
        const float4 e = ((const float4*)emb_table)[ch * 16 + e4];
        f16x4 ev = { (f16)e.x, (f16)e.y, (f16)e.z, (f16)e.w };
        *(f16x4*)&Xs[m * XSTR + HID + e4 * 4] = ev;
      }
    }

    // attention partials: this wave's 32 units, butterfly over r15 group
#pragma unroll
    for (int mt = 0; mt < 2; ++mt)
#pragma unroll
      for (int r = 0; r < 4; ++r) {
        const int i = mt * 4 + r;
        float p = h_new[0][i] * aw0 + h_new[1][i] * aw1;
        p += __shfl_xor(p, 1); p += __shfl_xor(p, 2);
        p += __shfl_xor(p, 4); p += __shfl_xor(p, 8);
        if (r15 == 0) attP[(mt * 16 + c4 * 4 + r) * 8 + wv] = p;
      }

    __syncthreads();

    // redundant per-lane weight: read 8 wave-partials (broadcast), sigm, mask, accumulate
#pragma unroll
    for (int mt = 0; mt < 2; ++mt)
#pragma unroll
      for (int r = 0; r < 4; ++r) {
        const int i = mt * 4 + r;
        const int w = mt * 16 + c4 * 4 + r;
        const f32x4 p0 = *(const f32x4*)&attP[w * 8];
        const f32x4 p1 = *(const f32x4*)&attP[w * 8 + 4];
        const float sum = (p0[0] + p0[1]) + (p0[2] + p0[3]) + (p1[0] + p1[1]) + (p1[2] + p1[3]);
        const float wgt = (t < lenr[i]) ? sigm(sum) : 0.0f;
        res[0][i] = fmaf(wgt, h_new[0][i], res[0][i]);
        res[1][i] = fmaf(wgt, h_new[1][i], res[1][i]);
      }
  }

  // ---- tensor_unsort + write
#pragma unroll
  for (int s = 0; s < 2; ++s)
#pragma unroll
    for (int mt = 0; mt < 2; ++mt)
#pragma unroll
      for (int r = 0; r < 4; ++r) {
        const int w = mt * 16 + c4 * 4 + r;
        out[(size_t)oidx_s[w] * HID + u0 + s * 16] = res[s][mt * 4 + r];
      }
}

extern "C" void kernel_launch(void* const* d_in, const int* in_sizes, int n_in,
                              void* d_out, int out_size, void* d_ws, size_t ws_size,
                              hipStream_t stream) {
  const int*   chars    = (const int*)d_in[0];
  const int*   wordlens = (const int*)d_in[1];
  const int*   orig_idx = (const int*)d_in[2];
  const float* emb      = (const float*)d_in[3];
  const float* W_ih     = (const float*)d_in[4];
  const float* W_hh     = (const float*)d_in[5];
  const float* b_ih     = (const float*)d_in[6];
  const float* b_hh     = (const float*)d_in[7];
  const float* attn_w   = (const float*)d_in[8];
  const float* h_init   = (const float*)d_in[9];
  const float* c_init   = (const float*)d_in[10];
  float* out = (float*)d_out;

  f16*   Wfrag2 = (f16*)d_ws;                      // 10*32768 f16 = 640 KiB (LDS image)
  float* bias_p = (float*)((char*)d_ws + (size_t)KT * 32768 * sizeof(f16));
  if (ws_size < (size_t)KT * 32768 * sizeof(f16) + 1024 * sizeof(float)) return;

  hipLaunchKernelGGL(prep_w, dim3(1024), dim3(KTOT), 0, stream,
                     W_ih, W_hh, b_ih, b_hh, Wfrag2, bias_p);
  hipLaunchKernelGGL(lstm_mfma, dim3(NBLK), dim3(THREADS), 0, stream,
                     chars, wordlens, orig_idx, emb, attn_w, h_init, c_init,
                     Wfrag2, bias_p, out);
}